// Round 3
// baseline (823.373 us; speedup 1.0000x reference)
//
#include <hip/hip_runtime.h>

#define NT      1024
#define NWAVES  (NT / 64)
#define COLS    32000
#define COLS4   (COLS / 4)     // 8000 float4 per row
#define PER     8              // ceil(8000 / 1024)
#define EPSF    1e-8f

__global__ __launch_bounds__(NT, 4) void SMSoftmax_12429635354922_kernel(
    const float* __restrict__ logits,
    const float* __restrict__ dist,
    float* __restrict__ out)
{
    __shared__ float redmax[NWAVES];
    __shared__ float redsum[NWAVES];

    const int row = blockIdx.x;
    const int tid = threadIdx.x;
    const float4* __restrict__ in4 =
        reinterpret_cast<const float4*>(logits) + (size_t)row * COLS4;
    float4* __restrict__ o4 =
        reinterpret_cast<float4*>(out) + (size_t)row * COLS4;

    // ---- load row into registers, tracking local max ----
    float4 v[PER];
    float m = -3.4e38f;
    #pragma unroll
    for (int k = 0; k < PER; ++k) {
        int idx = tid + k * NT;
        if (idx < COLS4) {
            v[k] = in4[idx];
            m = fmaxf(m, fmaxf(fmaxf(v[k].x, v[k].y), fmaxf(v[k].z, v[k].w)));
        }
    }

    // ---- block-wide max: wave butterfly + LDS across 16 waves ----
    #pragma unroll
    for (int off = 32; off > 0; off >>= 1)
        m = fmaxf(m, __shfl_xor(m, off, 64));
    const int wid = tid >> 6;
    if ((tid & 63) == 0) redmax[wid] = m;
    __syncthreads();
    #pragma unroll
    for (int w = 0; w < NWAVES; ++w) m = fmaxf(m, redmax[w]);

    // ---- e = exp(x - m + eps), accumulate row sum (overwrite v with e) ----
    float sum = 0.f;
    #pragma unroll
    for (int k = 0; k < PER; ++k) {
        int idx = tid + k * NT;
        if (idx < COLS4) {
            v[k].x = __expf(v[k].x - m + EPSF);
            v[k].y = __expf(v[k].y - m + EPSF);
            v[k].z = __expf(v[k].z - m + EPSF);
            v[k].w = __expf(v[k].w - m + EPSF);
            sum += (v[k].x + v[k].y) + (v[k].z + v[k].w);
        }
    }
    #pragma unroll
    for (int off = 32; off > 0; off >>= 1)
        sum += __shfl_xor(sum, off, 64);
    if ((tid & 63) == 0) redsum[wid] = sum;
    __syncthreads();
    float s = 0.f;
    #pragma unroll
    for (int w = 0; w < NWAVES; ++w) s += redsum[w];

    // ---- out = ed / (ed + s - e + eps), ed = e * exp(-dist) ----
    const float kd = __expf(-dist[0]);
    #pragma unroll
    for (int k = 0; k < PER; ++k) {
        int idx = tid + k * NT;
        if (idx < COLS4) {
            float4 r;
            float e, ed;
            e = v[k].x; ed = e * kd; r.x = ed / (((ed + s) - e) + EPSF);
            e = v[k].y; ed = e * kd; r.y = ed / (((ed + s) - e) + EPSF);
            e = v[k].z; ed = e * kd; r.z = ed / (((ed + s) - e) + EPSF);
            e = v[k].w; ed = e * kd; r.w = ed / (((ed + s) - e) + EPSF);
            o4[idx] = r;
        }
    }
}

extern "C" void kernel_launch(void* const* d_in, const int* in_sizes, int n_in,
                              void* d_out, int out_size, void* d_ws, size_t ws_size,
                              hipStream_t stream) {
    const float* logits = (const float*)d_in[0];
    const float* dist   = (const float*)d_in[1];
    float* out          = (float*)d_out;
    const int rows = in_sizes[0] / COLS;   // 4096
    SMSoftmax_12429635354922_kernel<<<rows, NT, 0, stream>>>(logits, dist, out);
}